// Round 8
// baseline (1436.861 us; speedup 1.0000x reference)
//
#include <hip/hip_runtime.h>
#include <hip/hip_bf16.h>
#include <hip/hip_fp16.h>

#define NFEAT 512
#define HID   64
#define NCLS  40

typedef short bf16x8 __attribute__((ext_vector_type(8)));
typedef float f32x4  __attribute__((ext_vector_type(4)));

__device__ inline short bfs(float f) {
  __hip_bfloat16 h = __float2bfloat16(f);
  return __builtin_bit_cast(short, h);
}
__device__ inline int pk(float a, float b) {  // two bf16 packed, a = low half
  return (int)(unsigned short)bfs(a) | ((int)(unsigned short)bfs(b) << 16);
}

// fp16 pack/unpack (8 halves <-> int4)
__device__ inline void up8(const int4 v, float f[8]) {
  float2 p;
  p = __half22float2(__builtin_bit_cast(__half2, v.x)); f[0] = p.x; f[1] = p.y;
  p = __half22float2(__builtin_bit_cast(__half2, v.y)); f[2] = p.x; f[3] = p.y;
  p = __half22float2(__builtin_bit_cast(__half2, v.z)); f[4] = p.x; f[5] = p.y;
  p = __half22float2(__builtin_bit_cast(__half2, v.w)); f[6] = p.x; f[7] = p.y;
}
__device__ inline int4 pk8(const float f[8]) {
  int4 r;
  r.x = __builtin_bit_cast(int, __floats2half2_rn(f[0], f[1]));
  r.y = __builtin_bit_cast(int, __floats2half2_rn(f[2], f[3]));
  r.z = __builtin_bit_cast(int, __floats2half2_rn(f[4], f[5]));
  r.w = __builtin_bit_cast(int, __floats2half2_rn(f[6], f[7]));
  return r;
}

// ---------------- degree / dinv ----------------

static __global__ void deg_i_kernel(const int* __restrict__ dst, int* __restrict__ deg, int E) {
  int e = blockIdx.x * blockDim.x + threadIdx.x;
  if (e < E) atomicAdd(&deg[dst[e]], 1);
}

static __global__ void dinv_kernel(const int* __restrict__ deg, float* __restrict__ dinv, int N) {
  int i = blockIdx.x * blockDim.x + threadIdx.x;
  if (i < N) dinv[i] = rsqrtf((float)deg[i] + 1.0f);
}

// ---------------- weight preconversion to bf16 ----------------
static __global__ void w1conv_kernel(const float* __restrict__ w1, short* __restrict__ w1bf) {
  int t = blockIdx.x * blockDim.x + threadIdx.x;  // 32768
  if (t >= NFEAT * HID) return;
  int k = t >> 6, n = t & 63;
  w1bf[n * NFEAT + k] = bfs(w1[k * HID + n]);
}
static __global__ void w2conv_kernel(const float* __restrict__ w2, short* __restrict__ w2bf) {
  int t = blockIdx.x * blockDim.x + threadIdx.x;  // 3072
  if (t >= 48 * HID) return;
  int n = t >> 6, k = t & 63;
  w2bf[t] = (n < NCLS) ? bfs(w2[k * NCLS + n]) : (short)0;
}

// ---------------- MFMA MLP ----------------
// Block: 256 threads (4 waves), 64 rows. Writes y0 = dinv*h (fp16) and out = g0*h (f32).
static __global__ __launch_bounds__(256) void mlp_mfma_kernel(
    const float* __restrict__ x, const short* __restrict__ w1bf, const float* __restrict__ b1,
    const short* __restrict__ w2bf, const float* __restrict__ b2, const float* __restrict__ temp,
    const float* __restrict__ dinv, __half* __restrict__ cur, float* __restrict__ out, int N)
{
  __shared__ __align__(16) short Al[64][72];
  __shared__ __align__(16) short Bl[64][72];
  __shared__ __align__(16) short Hl[64][72];
  __shared__ __align__(16) short W2l[48][72];
  const int tid = threadIdx.x;
  const int w = tid >> 6, lane = tid & 63;
  const int q = lane >> 4, m = lane & 15;
  const long row0 = (long)blockIdx.x * 64;

  if (tid < 192) {
    int n = tid >> 2, ch = tid & 3;
    const int4* sp = (const int4*)(w2bf + n * 64 + ch * 16);
    *(int4*)&W2l[n][ch * 16]     = sp[0];
    *(int4*)&W2l[n][ch * 16 + 8] = sp[1];
  }

  f32x4 zf = {0.f, 0.f, 0.f, 0.f};
  f32x4 acc[4] = {zf, zf, zf, zf};

  const int ar = tid >> 2, ch = tid & 3;
  const long gr = row0 + ar;

  for (int kk = 0; kk < NFEAT; kk += 64) {
    float4 v0, v1, v2, v3;
    if (gr < N) {
      const float4* xp = (const float4*)(x + gr * NFEAT + kk + ch * 16);
      v0 = xp[0]; v1 = xp[1]; v2 = xp[2]; v3 = xp[3];
    } else {
      v0 = v1 = v2 = v3 = make_float4(0.f, 0.f, 0.f, 0.f);
    }
    const int4* bp = (const int4*)(w1bf + ar * NFEAT + kk + ch * 16);
    int4 bv0 = bp[0], bv1 = bp[1];

    __syncthreads();
    int4 a0 = make_int4(pk(v0.x, v0.y), pk(v0.z, v0.w), pk(v1.x, v1.y), pk(v1.z, v1.w));
    int4 a1 = make_int4(pk(v2.x, v2.y), pk(v2.z, v2.w), pk(v3.x, v3.y), pk(v3.z, v3.w));
    *(int4*)&Al[ar][ch * 16]     = a0;
    *(int4*)&Al[ar][ch * 16 + 8] = a1;
    *(int4*)&Bl[ar][ch * 16]     = bv0;
    *(int4*)&Bl[ar][ch * 16 + 8] = bv1;
    __syncthreads();

    #pragma unroll
    for (int s = 0; s < 2; ++s) {
      bf16x8 a = *(const bf16x8*)&Al[w * 16 + m][s * 32 + q * 8];
      #pragma unroll
      for (int c = 0; c < 4; ++c) {
        bf16x8 b = *(const bf16x8*)&Bl[c * 16 + m][s * 32 + q * 8];
        acc[c] = __builtin_amdgcn_mfma_f32_16x16x32_bf16(a, b, acc[c], 0, 0, 0);
      }
    }
  }

  #pragma unroll
  for (int c = 0; c < 4; ++c) {
    int col = c * 16 + m;
    float bb = b1[col];
    #pragma unroll
    for (int r = 0; r < 4; ++r) {
      int rl = w * 16 + q * 4 + r;
      Hl[rl][col] = bfs(fmaxf(acc[c][r] + bb, 0.0f));
    }
  }
  __syncthreads();

  f32x4 acc2[3] = {zf, zf, zf};
  #pragma unroll
  for (int s = 0; s < 2; ++s) {
    bf16x8 a = *(const bf16x8*)&Hl[w * 16 + m][s * 32 + q * 8];
    #pragma unroll
    for (int c = 0; c < 3; ++c) {
      bf16x8 b = *(const bf16x8*)&W2l[c * 16 + m][s * 32 + q * 8];
      acc2[c] = __builtin_amdgcn_mfma_f32_16x16x32_bf16(a, b, acc2[c], 0, 0, 0);
    }
  }

  float g0 = fmaxf(temp[0], 0.0f);
  #pragma unroll
  for (int c = 0; c < 3; ++c) {
    int col = c * 16 + m;
    if (col < NCLS) {
      float bb = b2[col];
      #pragma unroll
      for (int r = 0; r < 4; ++r) {
        long grow = row0 + w * 16 + q * 4 + r;
        if (grow < N) {
          float vv = acc2[c][r] + bb;
          cur[grow * NCLS + col] = __float2half(dinv[grow] * vv);  // y0 = dinv*h
          out[grow * NCLS + col] = g0 * vv;
        }
      }
    }
  }
}

// ---------------- multi-block exclusive scan of deg -> rowptr/cursor ----------------

static __global__ __launch_bounds__(256) void scan1_kernel(const int* __restrict__ deg,
                                                           int* __restrict__ bsum, int N) {
  __shared__ int s[256];
  int tid = threadIdx.x;
  int i = blockIdx.x * 256 + tid;
  s[tid] = (i < N) ? deg[i] : 0;
  __syncthreads();
  for (int off = 128; off > 0; off >>= 1) {
    if (tid < off) s[tid] += s[tid + off];
    __syncthreads();
  }
  if (tid == 0) bsum[blockIdx.x] = s[0];
}

static __global__ __launch_bounds__(512) void scan2_kernel(int* __restrict__ bsum,
                                                           int* __restrict__ total, int nb) {
  __shared__ int s[512];
  int tid = threadIdx.x;
  int v = (tid < nb) ? bsum[tid] : 0;
  s[tid] = v;
  __syncthreads();
  for (int off = 1; off < 512; off <<= 1) {
    int t = (tid >= off) ? s[tid - off] : 0;
    __syncthreads();
    s[tid] += t;
    __syncthreads();
  }
  if (tid < nb) bsum[tid] = s[tid] - v;
  if (tid == 511) *total = s[511];
}

static __global__ __launch_bounds__(256) void scan3_kernel(const int* __restrict__ deg,
                                                           const int* __restrict__ bsum,
                                                           const int* __restrict__ total,
                                                           int* __restrict__ rowptr,
                                                           int* __restrict__ cursor, int N) {
  __shared__ int s[256];
  int tid = threadIdx.x;
  int i = blockIdx.x * 256 + tid;
  int v = (i < N) ? deg[i] : 0;
  s[tid] = v;
  __syncthreads();
  for (int off = 1; off < 256; off <<= 1) {
    int t = (tid >= off) ? s[tid - off] : 0;
    __syncthreads();
    s[tid] += t;
    __syncthreads();
  }
  if (i < N) {
    int e = bsum[blockIdx.x] + s[tid] - v;
    rowptr[i] = e;
    cursor[i] = e;
  }
  if (i == N) rowptr[N] = *total;
}

// ---------------- CSR fill ----------------
// EMPIRICAL (rounds 5/6/7): 8 B int2 scattered stores run 2x faster than 4 B int
// stores at identical WRITE_SIZE (~200 MB) and store count. Keep 8 B entries;
// only .x (src*5) is consumed by the gather.

static __global__ void fill_kernel(const int* __restrict__ src, const int* __restrict__ dst,
                                   int* __restrict__ cursor, int2* __restrict__ csr, int E) {
  int e = blockIdx.x * blockDim.x + threadIdx.x;
  if (e >= E) return;
  int s = src[e], d = dst[e];
  int pos = atomicAdd(&cursor[d], 1);
  csr[pos] = make_int2(s * 5, 0);
}

// ---------------- fused propagation step (CSR gather, y-form, fp16, unroll-8) ----------
// y' = dinv^2 * (y[row] + sum y[src]);  out += gamma*dinv*(y[row] + sum y[src])

static __global__ __launch_bounds__(256) void gather_kernel(
    const int* __restrict__ rowptr, const long* __restrict__ csr,
    const float* __restrict__ dinv, const float* __restrict__ temp, int k,
    const int4* __restrict__ cur, int4* __restrict__ nxt, float4* __restrict__ out, int n5)
{
  int t = blockIdx.x * blockDim.x + threadIdx.x;
  if (t >= n5) return;
  int row = t / 5, c4 = t - row * 5;
  int beg = rowptr[row], end = rowptr[row + 1];
  float dv = dinv[row];

  float a[8];
  up8(cur[t], a);   // self term y[row]

  int e = beg;
  // unroll-8: phase-separated (8 idx loads -> 8 gathers -> accumulate)
  for (; e + 7 < end; e += 8) {
    int idx[8];
    #pragma unroll
    for (int j = 0; j < 8; ++j)
      idx[j] = (int)__builtin_nontemporal_load(csr + e + j);   // low word = src*5
    int4 g[8];
    #pragma unroll
    for (int j = 0; j < 8; ++j) g[j] = cur[idx[j] + c4];
    #pragma unroll
    for (int j = 0; j < 8; ++j) {
      float u[8];
      up8(g[j], u);
      #pragma unroll
      for (int i = 0; i < 8; ++i) a[i] += u[i];
    }
  }
  for (; e + 1 < end; e += 2) {
    int i0 = (int)__builtin_nontemporal_load(csr + e);
    int i1 = (int)__builtin_nontemporal_load(csr + e + 1);
    int4 g0 = cur[i0 + c4];
    int4 g1 = cur[i1 + c4];
    float u0[8], u1[8];
    up8(g0, u0); up8(g1, u1);
    #pragma unroll
    for (int i = 0; i < 8; ++i) a[i] += u0[i] + u1[i];
  }
  if (e < end) {
    int i0 = (int)__builtin_nontemporal_load(csr + e);
    float u0[8];
    up8(cur[i0 + c4], u0);
    #pragma unroll
    for (int i = 0; i < 8; ++i) a[i] += u0[i];
  }

  float d2 = dv * dv;
  float y[8];
  #pragma unroll
  for (int i = 0; i < 8; ++i) y[i] = d2 * a[i];
  nxt[t] = pk8(y);

  float gd = fmaxf(temp[k], 0.0f) * dv;   // gamma * dinv
  int oi = row * 10 + c4 * 2;
  float4 o0 = out[oi], o1 = out[oi + 1];
  out[oi]     = make_float4(fmaf(gd, a[0], o0.x), fmaf(gd, a[1], o0.y), fmaf(gd, a[2], o0.z), fmaf(gd, a[3], o0.w));
  out[oi + 1] = make_float4(fmaf(gd, a[4], o1.x), fmaf(gd, a[5], o1.y), fmaf(gd, a[6], o1.z), fmaf(gd, a[7], o1.w));
}

// ---------------- fallback scatter path (only if ws too small) ----------------

static __global__ void selfloop_kernel(const float* __restrict__ dinv, const float4* __restrict__ cur,
                                       float4* __restrict__ nxt, int n10) {
  int t = blockIdx.x * blockDim.x + threadIdx.x;
  if (t >= n10) return;
  int i = t / 10;
  float dv = dinv[i], s = dv * dv;
  float4 v = cur[t];
  nxt[t] = make_float4(s * v.x, s * v.y, s * v.z, s * v.w);
}

static __global__ void scatter_kernel(const int* __restrict__ src, const int* __restrict__ dst,
                                      const float* __restrict__ dinv,
                                      const float4* __restrict__ cur, float* __restrict__ nxt, int items) {
  int t = blockIdx.x * blockDim.x + threadIdx.x;
  if (t >= items) return;
  int e = t / 10, c4 = t - e * 10;
  int s = src[e], d = dst[e];
  float nm = dinv[s] * dinv[d];
  float4 v = cur[s * 10 + c4];
  float* np = nxt + (size_t)d * NCLS + c4 * 4;
  unsafeAtomicAdd(np + 0, nm * v.x);
  unsafeAtomicAdd(np + 1, nm * v.y);
  unsafeAtomicAdd(np + 2, nm * v.z);
  unsafeAtomicAdd(np + 3, nm * v.w);
}

static __global__ void axpy_kernel(const float* __restrict__ temp, int k,
                                   const float4* __restrict__ nxt, float4* __restrict__ out, int n10) {
  int t = blockIdx.x * blockDim.x + threadIdx.x;
  if (t >= n10) return;
  float g = fmaxf(temp[k], 0.0f);
  float4 v = nxt[t], o = out[t];
  out[t] = make_float4(o.x + g * v.x, o.y + g * v.y, o.z + g * v.z, o.w + g * v.w);
}

static __global__ __launch_bounds__(256) void mlp_kernel(
    const float* __restrict__ x, const float* __restrict__ w1, const float* __restrict__ b1,
    const float* __restrict__ w2, const float* __restrict__ b2, const float* __restrict__ temp,
    float* __restrict__ cur, float* __restrict__ out, int N)
{
  __shared__ __align__(16) float xs[4][NFEAT];
  __shared__ float hs[4][HID];
  const int w = threadIdx.x >> 6, lane = threadIdx.x & 63;
  const int i = blockIdx.x * 4 + w;
  if (i < N) {
    const float4* xrow = (const float4*)(x + (size_t)i * NFEAT);
    float4* xsr = (float4*)xs[w];
    xsr[lane]      = xrow[lane];
    xsr[lane + 64] = xrow[lane + 64];
  }
  __syncthreads();
  if (i < N) {
    float acc = b1[lane];
    #pragma unroll 8
    for (int k = 0; k < NFEAT; ++k)
      acc = fmaf(xs[w][k], w1[k * HID + lane], acc);
    hs[w][lane] = fmaxf(acc, 0.0f);
  }
  __syncthreads();
  if (i < N && lane < NCLS) {
    float a2 = b2[lane];
    #pragma unroll
    for (int j = 0; j < HID; ++j)
      a2 = fmaf(hs[w][j], w2[j * NCLS + lane], a2);
    float g0 = fmaxf(temp[0], 0.0f);
    cur[(size_t)i * NCLS + lane] = a2;
    out[(size_t)i * NCLS + lane] = g0 * a2;
  }
}

// ---------------- log_softmax ----------------
static __global__ void logsoftmax_kernel(float* __restrict__ out, int N) {
  int i = blockIdx.x * blockDim.x + threadIdx.x;
  if (i >= N) return;
  float4* row = (float4*)(out + (size_t)i * NCLS);
  float4 v[10];
  float m = -3.4e38f;
  #pragma unroll
  for (int r = 0; r < 10; ++r) {
    v[r] = row[r];
    m = fmaxf(m, fmaxf(fmaxf(v[r].x, v[r].y), fmaxf(v[r].z, v[r].w)));
  }
  float sum = 0.0f;
  #pragma unroll
  for (int r = 0; r < 10; ++r)
    sum += __expf(v[r].x - m) + __expf(v[r].y - m) + __expf(v[r].z - m) + __expf(v[r].w - m);
  float l = m + __logf(sum);
  #pragma unroll
  for (int r = 0; r < 10; ++r)
    row[r] = make_float4(v[r].x - l, v[r].y - l, v[r].z - l, v[r].w - l);
}

// ---------------- launch ----------------

extern "C" void kernel_launch(void* const* d_in, const int* in_sizes, int n_in,
                              void* d_out, int out_size, void* d_ws, size_t ws_size,
                              hipStream_t stream) {
  const float* x    = (const float*)d_in[0];
  const int*   ei   = (const int*)d_in[1];
  const float* w1   = (const float*)d_in[2];
  const float* b1   = (const float*)d_in[3];
  const float* w2   = (const float*)d_in[4];
  const float* b2   = (const float*)d_in[5];
  const float* temp = (const float*)d_in[6];

  const int N = in_sizes[0] / NFEAT;   // 100000
  const int E = in_sizes[1] / 2;       // 3200000
  const int* src = ei;
  const int* dst = ei + E;
  float* out = (float*)d_out;

  char* ws = (char*)d_ws;
  size_t off = 0;
  auto alloc = [&](size_t bytes) { size_t o = off; off += (bytes + 255) & ~(size_t)255; return o; };
  float* dinv   = (float*)(ws + alloc((size_t)N * 4));
  int*   deg    = (int*)  (ws + alloc((size_t)N * 4));
  float* curA   = (float*)(ws + alloc((size_t)N * NCLS * 4));  // fp16 in main path
  float* curB   = (float*)(ws + alloc((size_t)N * NCLS * 4));
  int*   rowptr = (int*)  (ws + alloc((size_t)(N + 1) * 4));
  int*   cursor = (int*)  (ws + alloc((size_t)N * 4));
  int*   bsum   = (int*)  (ws + alloc(1024 * 4));
  int*   total  = (int*)  (ws + alloc(256));
  short* w1bf   = (short*)(ws + alloc((size_t)NFEAT * HID * 2));
  short* w2bf   = (short*)(ws + alloc((size_t)48 * HID * 2));
  int2*  csr    = (int2*) (ws + alloc((size_t)E * 8));
  const bool csr_ok = (off <= ws_size);

  hipMemsetAsync(deg, 0, (size_t)N * sizeof(int), stream);
  deg_i_kernel<<<(E + 255) / 256, 256, 0, stream>>>(dst, deg, E);
  dinv_kernel<<<(N + 255) / 256, 256, 0, stream>>>(deg, dinv, N);

  if (csr_ok) {
    w1conv_kernel<<<(NFEAT * HID + 255) / 256, 256, 0, stream>>>(w1, w1bf);
    w2conv_kernel<<<(48 * HID + 255) / 256, 256, 0, stream>>>(w2, w2bf);
    mlp_mfma_kernel<<<(N + 63) / 64, 256, 0, stream>>>(x, w1bf, b1, w2bf, b2, temp, dinv,
                                                       (__half*)curA, out, N);

    const int nb = (N + 255) / 256;
    scan1_kernel<<<nb, 256, 0, stream>>>(deg, bsum, N);
    scan2_kernel<<<1, 512, 0, stream>>>(bsum, total, nb);
    scan3_kernel<<<(N + 256) / 256, 256, 0, stream>>>(deg, bsum, total, rowptr, cursor, N);
    fill_kernel<<<(E + 255) / 256, 256, 0, stream>>>(src, dst, cursor, csr, E);

    const int n5 = N * 5;
    int4* cur = (int4*)curA;
    int4* nxt = (int4*)curB;
    for (int k = 0; k < 10; ++k) {
      gather_kernel<<<(n5 + 255) / 256, 256, 0, stream>>>(
          rowptr, (const long*)csr, dinv, temp, k + 1, cur, nxt, (float4*)out, n5);
      int4* t2 = cur; cur = nxt; nxt = t2;
    }
  } else {
    mlp_kernel<<<(N + 3) / 4, 256, 0, stream>>>(x, w1, b1, w2, b2, temp, curA, out, N);
    const int n10 = N * 10;
    const int items = E * 10;
    float* cur = curA;
    float* nxt = curB;
    for (int k = 0; k < 10; ++k) {
      selfloop_kernel<<<(n10 + 255) / 256, 256, 0, stream>>>(dinv, (const float4*)cur, (float4*)nxt, n10);
      scatter_kernel<<<(items + 255) / 256, 256, 0, stream>>>(src, dst, dinv, (const float4*)cur, nxt, items);
      axpy_kernel<<<(n10 + 255) / 256, 256, 0, stream>>>(temp, k + 1, (const float4*)nxt, (float4*)out, n10);
      float* t2 = cur; cur = nxt; nxt = t2;
    }
  }

  logsoftmax_kernel<<<(N + 255) / 256, 256, 0, stream>>>(out, N);
}

// Round 9
// 1254.665 us; speedup vs baseline: 1.1452x; 1.1452x over previous
//
#include <hip/hip_runtime.h>
#include <hip/hip_bf16.h>
#include <hip/hip_fp16.h>
#include <hip/hip_fp8.h>

#define NFEAT 512
#define HID   64
#define NCLS  40

typedef short bf16x8 __attribute__((ext_vector_type(8)));
typedef float f32x4  __attribute__((ext_vector_type(4)));
typedef float v2f    __attribute__((ext_vector_type(2)));

__device__ inline short bfs(float f) {
  __hip_bfloat16 h = __float2bfloat16(f);
  return __builtin_bit_cast(short, h);
}
__device__ inline int pk(float a, float b) {  // two bf16 packed, a = low half
  return (int)(unsigned short)bfs(a) | ((int)(unsigned short)bfs(b) << 16);
}

// ---- fp8 e4m3 (OCP) pack/unpack: 8 fp8 <-> int2 ----
__device__ inline void up8f8(const int2 v, float f[8]) {
#if __has_builtin(__builtin_amdgcn_cvt_pk_f32_fp8)
  v2f p;
  p = __builtin_amdgcn_cvt_pk_f32_fp8(v.x, false); f[0] = p[0]; f[1] = p[1];
  p = __builtin_amdgcn_cvt_pk_f32_fp8(v.x, true);  f[2] = p[0]; f[3] = p[1];
  p = __builtin_amdgcn_cvt_pk_f32_fp8(v.y, false); f[4] = p[0]; f[5] = p[1];
  p = __builtin_amdgcn_cvt_pk_f32_fp8(v.y, true);  f[6] = p[0]; f[7] = p[1];
#else
  const unsigned char* b = (const unsigned char*)&v;
  #pragma unroll
  for (int i = 0; i < 8; ++i) { __hip_fp8_e4m3 h; h.__x = b[i]; f[i] = (float)h; }
#endif
}
__device__ inline int2 pk8f8(const float f[8]) {
#if __has_builtin(__builtin_amdgcn_cvt_pk_fp8_f32)
  int lo = 0, hi = 0;
  lo = __builtin_amdgcn_cvt_pk_fp8_f32(f[0], f[1], lo, false);
  lo = __builtin_amdgcn_cvt_pk_fp8_f32(f[2], f[3], lo, true);
  hi = __builtin_amdgcn_cvt_pk_fp8_f32(f[4], f[5], hi, false);
  hi = __builtin_amdgcn_cvt_pk_fp8_f32(f[6], f[7], hi, true);
  return make_int2(lo, hi);
#else
  int2 r; unsigned char* b = (unsigned char*)&r;
  #pragma unroll
  for (int i = 0; i < 8; ++i) { __hip_fp8_e4m3 h((float)f[i]); b[i] = h.__x; }
  return r;
#endif
}
__device__ inline unsigned char f8b(float v) {
#if __has_builtin(__builtin_amdgcn_cvt_pk_fp8_f32)
  int r = __builtin_amdgcn_cvt_pk_fp8_f32(v, v, 0, false);
  return (unsigned char)(r & 0xff);
#else
  __hip_fp8_e4m3 h(v); return h.__x;
#endif
}

// ---------------- degree / dinv ----------------

static __global__ void deg_i_kernel(const int* __restrict__ dst, int* __restrict__ deg, int E) {
  int e = blockIdx.x * blockDim.x + threadIdx.x;
  if (e < E) atomicAdd(&deg[dst[e]], 1);
}

static __global__ void dinv_kernel(const int* __restrict__ deg, float* __restrict__ dinv, int N) {
  int i = blockIdx.x * blockDim.x + threadIdx.x;
  if (i < N) dinv[i] = rsqrtf((float)deg[i] + 1.0f);
}

// ---------------- weight preconversion to bf16 ----------------
static __global__ void w1conv_kernel(const float* __restrict__ w1, short* __restrict__ w1bf) {
  int t = blockIdx.x * blockDim.x + threadIdx.x;  // 32768
  if (t >= NFEAT * HID) return;
  int k = t >> 6, n = t & 63;
  w1bf[n * NFEAT + k] = bfs(w1[k * HID + n]);
}
static __global__ void w2conv_kernel(const float* __restrict__ w2, short* __restrict__ w2bf) {
  int t = blockIdx.x * blockDim.x + threadIdx.x;  // 3072
  if (t >= 48 * HID) return;
  int n = t >> 6, k = t & 63;
  w2bf[t] = (n < NCLS) ? bfs(w2[k * NCLS + n]) : (short)0;
}

// ---------------- MFMA MLP ----------------
// Block: 256 threads (4 waves), 64 rows. Writes y0 = dinv*h as fp8 (64 B row stride)
// and out = g0*h (f32).
static __global__ __launch_bounds__(256) void mlp_mfma_kernel(
    const float* __restrict__ x, const short* __restrict__ w1bf, const float* __restrict__ b1,
    const short* __restrict__ w2bf, const float* __restrict__ b2, const float* __restrict__ temp,
    const float* __restrict__ dinv, unsigned char* __restrict__ cur, float* __restrict__ out, int N)
{
  __shared__ __align__(16) short Al[64][72];
  __shared__ __align__(16) short Bl[64][72];
  __shared__ __align__(16) short Hl[64][72];
  __shared__ __align__(16) short W2l[48][72];
  const int tid = threadIdx.x;
  const int w = tid >> 6, lane = tid & 63;
  const int q = lane >> 4, m = lane & 15;
  const long row0 = (long)blockIdx.x * 64;

  if (tid < 192) {
    int n = tid >> 2, ch = tid & 3;
    const int4* sp = (const int4*)(w2bf + n * 64 + ch * 16);
    *(int4*)&W2l[n][ch * 16]     = sp[0];
    *(int4*)&W2l[n][ch * 16 + 8] = sp[1];
  }

  f32x4 zf = {0.f, 0.f, 0.f, 0.f};
  f32x4 acc[4] = {zf, zf, zf, zf};

  const int ar = tid >> 2, ch = tid & 3;
  const long gr = row0 + ar;

  for (int kk = 0; kk < NFEAT; kk += 64) {
    float4 v0, v1, v2, v3;
    if (gr < N) {
      const float4* xp = (const float4*)(x + gr * NFEAT + kk + ch * 16);
      v0 = xp[0]; v1 = xp[1]; v2 = xp[2]; v3 = xp[3];
    } else {
      v0 = v1 = v2 = v3 = make_float4(0.f, 0.f, 0.f, 0.f);
    }
    const int4* bp = (const int4*)(w1bf + ar * NFEAT + kk + ch * 16);
    int4 bv0 = bp[0], bv1 = bp[1];

    __syncthreads();
    int4 a0 = make_int4(pk(v0.x, v0.y), pk(v0.z, v0.w), pk(v1.x, v1.y), pk(v1.z, v1.w));
    int4 a1 = make_int4(pk(v2.x, v2.y), pk(v2.z, v2.w), pk(v3.x, v3.y), pk(v3.z, v3.w));
    *(int4*)&Al[ar][ch * 16]     = a0;
    *(int4*)&Al[ar][ch * 16 + 8] = a1;
    *(int4*)&Bl[ar][ch * 16]     = bv0;
    *(int4*)&Bl[ar][ch * 16 + 8] = bv1;
    __syncthreads();

    #pragma unroll
    for (int s = 0; s < 2; ++s) {
      bf16x8 a = *(const bf16x8*)&Al[w * 16 + m][s * 32 + q * 8];
      #pragma unroll
      for (int c = 0; c < 4; ++c) {
        bf16x8 b = *(const bf16x8*)&Bl[c * 16 + m][s * 32 + q * 8];
        acc[c] = __builtin_amdgcn_mfma_f32_16x16x32_bf16(a, b, acc[c], 0, 0, 0);
      }
    }
  }

  #pragma unroll
  for (int c = 0; c < 4; ++c) {
    int col = c * 16 + m;
    float bb = b1[col];
    #pragma unroll
    for (int r = 0; r < 4; ++r) {
      int rl = w * 16 + q * 4 + r;
      Hl[rl][col] = bfs(fmaxf(acc[c][r] + bb, 0.0f));
    }
  }
  __syncthreads();

  f32x4 acc2[3] = {zf, zf, zf};
  #pragma unroll
  for (int s = 0; s < 2; ++s) {
    bf16x8 a = *(const bf16x8*)&Hl[w * 16 + m][s * 32 + q * 8];
    #pragma unroll
    for (int c = 0; c < 3; ++c) {
      bf16x8 b = *(const bf16x8*)&W2l[c * 16 + m][s * 32 + q * 8];
      acc2[c] = __builtin_amdgcn_mfma_f32_16x16x32_bf16(a, b, acc2[c], 0, 0, 0);
    }
  }

  float g0 = fmaxf(temp[0], 0.0f);
  #pragma unroll
  for (int c = 0; c < 3; ++c) {
    int col = c * 16 + m;
    if (col < NCLS) {
      float bb = b2[col];
      #pragma unroll
      for (int r = 0; r < 4; ++r) {
        long grow = row0 + w * 16 + q * 4 + r;
        if (grow < N) {
          float vv = acc2[c][r] + bb;
          cur[grow * 64 + col] = f8b(dinv[grow] * vv);  // y0 = dinv*h, fp8
          out[grow * NCLS + col] = g0 * vv;
        }
      }
    }
  }
}

// ---------------- multi-block exclusive scan of deg -> rowptr/cursor ----------------

static __global__ __launch_bounds__(256) void scan1_kernel(const int* __restrict__ deg,
                                                           int* __restrict__ bsum, int N) {
  __shared__ int s[256];
  int tid = threadIdx.x;
  int i = blockIdx.x * 256 + tid;
  s[tid] = (i < N) ? deg[i] : 0;
  __syncthreads();
  for (int off = 128; off > 0; off >>= 1) {
    if (tid < off) s[tid] += s[tid + off];
    __syncthreads();
  }
  if (tid == 0) bsum[blockIdx.x] = s[0];
}

static __global__ __launch_bounds__(512) void scan2_kernel(int* __restrict__ bsum,
                                                           int* __restrict__ total, int nb) {
  __shared__ int s[512];
  int tid = threadIdx.x;
  int v = (tid < nb) ? bsum[tid] : 0;
  s[tid] = v;
  __syncthreads();
  for (int off = 1; off < 512; off <<= 1) {
    int t = (tid >= off) ? s[tid - off] : 0;
    __syncthreads();
    s[tid] += t;
    __syncthreads();
  }
  if (tid < nb) bsum[tid] = s[tid] - v;
  if (tid == 511) *total = s[511];
}

static __global__ __launch_bounds__(256) void scan3_kernel(const int* __restrict__ deg,
                                                           const int* __restrict__ bsum,
                                                           const int* __restrict__ total,
                                                           int* __restrict__ rowptr,
                                                           int* __restrict__ cursor, int N) {
  __shared__ int s[256];
  int tid = threadIdx.x;
  int i = blockIdx.x * 256 + tid;
  int v = (i < N) ? deg[i] : 0;
  s[tid] = v;
  __syncthreads();
  for (int off = 1; off < 256; off <<= 1) {
    int t = (tid >= off) ? s[tid - off] : 0;
    __syncthreads();
    s[tid] += t;
    __syncthreads();
  }
  if (i < N) {
    int e = bsum[blockIdx.x] + s[tid] - v;
    rowptr[i] = e;
    cursor[i] = e;
  }
  if (i == N) rowptr[N] = *total;
}

// ---------------- CSR fill: src node id (4 B) ----------------
// Scattered-store transaction floor ~280-300 us regardless of 4B/8B width
// (r5's 157 us was a session anomaly; r6/7/8 evidence). Keep 4B: halves the
// gather-side csr stream.

static __global__ void fill_kernel(const int* __restrict__ src, const int* __restrict__ dst,
                                   int* __restrict__ cursor, int* __restrict__ csr, int E) {
  int e = blockIdx.x * blockDim.x + threadIdx.x;
  if (e >= E) return;
  int s = src[e], d = dst[e];
  int pos = atomicAdd(&cursor[d], 1);
  csr[pos] = s;
}

// ---------------- fused propagation step (CSR gather, y-form, fp8, unroll-8) ----------
// cur rows: 40 fp8 bytes padded to 64 B stride -> exactly ONE cache line per edge.
// y' = dinv^2 * (y[row] + sum y[src]);  out += gamma*dinv*(y[row] + sum y[src])

static __global__ __launch_bounds__(256) void gather_kernel(
    const int* __restrict__ rowptr, const int* __restrict__ csr,
    const float* __restrict__ dinv, const float* __restrict__ temp, int k,
    const unsigned char* __restrict__ cur, unsigned char* __restrict__ nxt,
    float4* __restrict__ out, int n5)
{
  int t = blockIdx.x * blockDim.x + threadIdx.x;
  if (t >= n5) return;
  int row = t / 5, c4 = t - row * 5;
  int c8 = c4 * 8;
  int beg = rowptr[row], end = rowptr[row + 1];
  float dv = dinv[row];

  float a[8];
  up8f8(*(const int2*)(cur + (row << 6) + c8), a);   // self term y[row]

  int e = beg;
  // unroll-8: phase-separated (8 idx loads -> 8 gathers -> accumulate)
  for (; e + 7 < end; e += 8) {
    int idx[8];
    #pragma unroll
    for (int j = 0; j < 8; ++j) idx[j] = __builtin_nontemporal_load(csr + e + j);
    int2 g[8];
    #pragma unroll
    for (int j = 0; j < 8; ++j) g[j] = *(const int2*)(cur + ((long)idx[j] << 6) + c8);
    #pragma unroll
    for (int j = 0; j < 8; ++j) {
      float u[8];
      up8f8(g[j], u);
      #pragma unroll
      for (int i = 0; i < 8; ++i) a[i] += u[i];
    }
  }
  for (; e + 1 < end; e += 2) {
    int i0 = __builtin_nontemporal_load(csr + e);
    int i1 = __builtin_nontemporal_load(csr + e + 1);
    int2 g0 = *(const int2*)(cur + ((long)i0 << 6) + c8);
    int2 g1 = *(const int2*)(cur + ((long)i1 << 6) + c8);
    float u0[8], u1[8];
    up8f8(g0, u0); up8f8(g1, u1);
    #pragma unroll
    for (int i = 0; i < 8; ++i) a[i] += u0[i] + u1[i];
  }
  if (e < end) {
    int i0 = __builtin_nontemporal_load(csr + e);
    float u0[8];
    up8f8(*(const int2*)(cur + ((long)i0 << 6) + c8), u0);
    #pragma unroll
    for (int i = 0; i < 8; ++i) a[i] += u0[i];
  }

  float d2 = dv * dv;
  float y[8];
  #pragma unroll
  for (int i = 0; i < 8; ++i) y[i] = d2 * a[i];
  *(int2*)(nxt + (row << 6) + c8) = pk8f8(y);

  float gd = fmaxf(temp[k], 0.0f) * dv;   // gamma * dinv
  int oi = row * 10 + c4 * 2;
  float4 o0 = out[oi], o1 = out[oi + 1];
  out[oi]     = make_float4(fmaf(gd, a[0], o0.x), fmaf(gd, a[1], o0.y), fmaf(gd, a[2], o0.z), fmaf(gd, a[3], o0.w));
  out[oi + 1] = make_float4(fmaf(gd, a[4], o1.x), fmaf(gd, a[5], o1.y), fmaf(gd, a[6], o1.z), fmaf(gd, a[7], o1.w));
}

// ---------------- fallback scatter path (only if ws too small) ----------------

static __global__ void selfloop_kernel(const float* __restrict__ dinv, const float4* __restrict__ cur,
                                       float4* __restrict__ nxt, int n10) {
  int t = blockIdx.x * blockDim.x + threadIdx.x;
  if (t >= n10) return;
  int i = t / 10;
  float dv = dinv[i], s = dv * dv;
  float4 v = cur[t];
  nxt[t] = make_float4(s * v.x, s * v.y, s * v.z, s * v.w);
}

static __global__ void scatter_kernel(const int* __restrict__ src, const int* __restrict__ dst,
                                      const float* __restrict__ dinv,
                                      const float4* __restrict__ cur, float* __restrict__ nxt, int items) {
  int t = blockIdx.x * blockDim.x + threadIdx.x;
  if (t >= items) return;
  int e = t / 10, c4 = t - e * 10;
  int s = src[e], d = dst[e];
  float nm = dinv[s] * dinv[d];
  float4 v = cur[s * 10 + c4];
  float* np = nxt + (size_t)d * NCLS + c4 * 4;
  unsafeAtomicAdd(np + 0, nm * v.x);
  unsafeAtomicAdd(np + 1, nm * v.y);
  unsafeAtomicAdd(np + 2, nm * v.z);
  unsafeAtomicAdd(np + 3, nm * v.w);
}

static __global__ void axpy_kernel(const float* __restrict__ temp, int k,
                                   const float4* __restrict__ nxt, float4* __restrict__ out, int n10) {
  int t = blockIdx.x * blockDim.x + threadIdx.x;
  if (t >= n10) return;
  float g = fmaxf(temp[k], 0.0f);
  float4 v = nxt[t], o = out[t];
  out[t] = make_float4(o.x + g * v.x, o.y + g * v.y, o.z + g * v.z, o.w + g * v.w);
}

static __global__ __launch_bounds__(256) void mlp_kernel(
    const float* __restrict__ x, const float* __restrict__ w1, const float* __restrict__ b1,
    const float* __restrict__ w2, const float* __restrict__ b2, const float* __restrict__ temp,
    float* __restrict__ cur, float* __restrict__ out, int N)
{
  __shared__ __align__(16) float xs[4][NFEAT];
  __shared__ float hs[4][HID];
  const int w = threadIdx.x >> 6, lane = threadIdx.x & 63;
  const int i = blockIdx.x * 4 + w;
  if (i < N) {
    const float4* xrow = (const float4*)(x + (size_t)i * NFEAT);
    float4* xsr = (float4*)xs[w];
    xsr[lane]      = xrow[lane];
    xsr[lane + 64] = xrow[lane + 64];
  }
  __syncthreads();
  if (i < N) {
    float acc = b1[lane];
    #pragma unroll 8
    for (int k = 0; k < NFEAT; ++k)
      acc = fmaf(xs[w][k], w1[k * HID + lane], acc);
    hs[w][lane] = fmaxf(acc, 0.0f);
  }
  __syncthreads();
  if (i < N && lane < NCLS) {
    float a2 = b2[lane];
    #pragma unroll
    for (int j = 0; j < HID; ++j)
      a2 = fmaf(hs[w][j], w2[j * NCLS + lane], a2);
    float g0 = fmaxf(temp[0], 0.0f);
    cur[(size_t)i * NCLS + lane] = a2;
    out[(size_t)i * NCLS + lane] = g0 * a2;
  }
}

// ---------------- log_softmax ----------------
static __global__ void logsoftmax_kernel(float* __restrict__ out, int N) {
  int i = blockIdx.x * blockDim.x + threadIdx.x;
  if (i >= N) return;
  float4* row = (float4*)(out + (size_t)i * NCLS);
  float4 v[10];
  float m = -3.4e38f;
  #pragma unroll
  for (int r = 0; r < 10; ++r) {
    v[r] = row[r];
    m = fmaxf(m, fmaxf(fmaxf(v[r].x, v[r].y), fmaxf(v[r].z, v[r].w)));
  }
  float sum = 0.0f;
  #pragma unroll
  for (int r = 0; r < 10; ++r)
    sum += __expf(v[r].x - m) + __expf(v[r].y - m) + __expf(v[r].z - m) + __expf(v[r].w - m);
  float l = m + __logf(sum);
  #pragma unroll
  for (int r = 0; r < 10; ++r)
    row[r] = make_float4(v[r].x - l, v[r].y - l, v[r].z - l, v[r].w - l);
}

// ---------------- launch ----------------

extern "C" void kernel_launch(void* const* d_in, const int* in_sizes, int n_in,
                              void* d_out, int out_size, void* d_ws, size_t ws_size,
                              hipStream_t stream) {
  const float* x    = (const float*)d_in[0];
  const int*   ei   = (const int*)d_in[1];
  const float* w1   = (const float*)d_in[2];
  const float* b1   = (const float*)d_in[3];
  const float* w2   = (const float*)d_in[4];
  const float* b2   = (const float*)d_in[5];
  const float* temp = (const float*)d_in[6];

  const int N = in_sizes[0] / NFEAT;   // 100000
  const int E = in_sizes[1] / 2;       // 3200000
  const int* src = ei;
  const int* dst = ei + E;
  float* out = (float*)d_out;

  char* ws = (char*)d_ws;
  size_t off = 0;
  auto alloc = [&](size_t bytes) { size_t o = off; off += (bytes + 255) & ~(size_t)255; return o; };
  float* dinv   = (float*)(ws + alloc((size_t)N * 4));
  int*   deg    = (int*)  (ws + alloc((size_t)N * 4));
  unsigned char* curA = (unsigned char*)(ws + alloc((size_t)N * 64));  // fp8, 64 B rows
  unsigned char* curB = (unsigned char*)(ws + alloc((size_t)N * 64));
  int*   rowptr = (int*)  (ws + alloc((size_t)(N + 1) * 4));
  int*   cursor = (int*)  (ws + alloc((size_t)N * 4));
  int*   bsum   = (int*)  (ws + alloc(1024 * 4));
  int*   total  = (int*)  (ws + alloc(256));
  short* w1bf   = (short*)(ws + alloc((size_t)NFEAT * HID * 2));
  short* w2bf   = (short*)(ws + alloc((size_t)48 * HID * 2));
  int*   csr    = (int*)  (ws + alloc((size_t)E * 4));
  // fallback needs f32 cur buffers
  float* fA     = (float*)curA;
  const bool csr_ok = (off <= ws_size);

  hipMemsetAsync(deg, 0, (size_t)N * sizeof(int), stream);
  deg_i_kernel<<<(E + 255) / 256, 256, 0, stream>>>(dst, deg, E);
  dinv_kernel<<<(N + 255) / 256, 256, 0, stream>>>(deg, dinv, N);

  if (csr_ok) {
    w1conv_kernel<<<(NFEAT * HID + 255) / 256, 256, 0, stream>>>(w1, w1bf);
    w2conv_kernel<<<(48 * HID + 255) / 256, 256, 0, stream>>>(w2, w2bf);
    mlp_mfma_kernel<<<(N + 63) / 64, 256, 0, stream>>>(x, w1bf, b1, w2bf, b2, temp, dinv,
                                                       curA, out, N);

    const int nb = (N + 255) / 256;
    scan1_kernel<<<nb, 256, 0, stream>>>(deg, bsum, N);
    scan2_kernel<<<1, 512, 0, stream>>>(bsum, total, nb);
    scan3_kernel<<<(N + 256) / 256, 256, 0, stream>>>(deg, bsum, total, rowptr, cursor, N);
    fill_kernel<<<(E + 255) / 256, 256, 0, stream>>>(src, dst, cursor, csr, E);

    const int n5 = N * 5;
    unsigned char* cur = curA;
    unsigned char* nxt = curB;
    for (int k = 0; k < 10; ++k) {
      gather_kernel<<<(n5 + 255) / 256, 256, 0, stream>>>(
          rowptr, csr, dinv, temp, k + 1, cur, nxt, (float4*)out, n5);
      unsigned char* t2 = cur; cur = nxt; nxt = t2;
    }
  } else {
    // f32 fallback (uses curA region as float storage; requires less ws than main path)
    float* fB = (float*)curB;
    mlp_kernel<<<(N + 3) / 4, 256, 0, stream>>>(x, w1, b1, w2, b2, temp, fA, out, N);
    const int n10 = N * 10;
    const int items = E * 10;
    float* cur = fA;
    float* nxt = fB;
    for (int k = 0; k < 10; ++k) {
      selfloop_kernel<<<(n10 + 255) / 256, 256, 0, stream>>>(dinv, (const float4*)cur, (float4*)nxt, n10);
      scatter_kernel<<<(items + 255) / 256, 256, 0, stream>>>(src, dst, dinv, (const float4*)cur, nxt, items);
      axpy_kernel<<<(n10 + 255) / 256, 256, 0, stream>>>(temp, k + 1, (const float4*)nxt, (float4*)out, n10);
      float* t2 = cur; cur = nxt; nxt = t2;
    }
  }

  logsoftmax_kernel<<<(N + 255) / 256, 256, 0, stream>>>(out, N);
}